// Round 7
// baseline (307.161 us; speedup 1.0000x reference)
//
#include <hip/hip_runtime.h>
#include <hip/hip_bf16.h>

#define B_ 2
#define S_ 2048
#define E_ 1024
#define H_ 16
#define D_ 64
#define NE_ 8
#define TOKENS (B_*S_)   // 4096
#define QSCALE 0.18033688011112043f   // log2(e)/8, folded into Q

typedef __attribute__((ext_vector_type(8))) short bf16x8;
typedef __attribute__((ext_vector_type(4))) float f32x4;
typedef unsigned short u16;
typedef unsigned int u32;

__device__ __forceinline__ u16 f2bf(float f) {
    u32 u = __float_as_uint(f);
    u32 r = u + 0x7fffu + ((u >> 16) & 1u);
    return (u16)(r >> 16);
}
__device__ __forceinline__ float bf2f(u16 h) {
    return __uint_as_float(((u32)h) << 16);
}
__device__ __forceinline__ void gl2lds16(const void* g, void* l) {
    __builtin_amdgcn_global_load_lds(
        (__attribute__((address_space(1))) void*)(g),
        (__attribute__((address_space(3))) void*)(l), 16, 0, 0);
}
#define MFMA16(a,b,c) __builtin_amdgcn_mfma_f32_16x16x32_bf16(a,b,c,0,0,0)

// ---------------------------------------------------------------------------
// Fused fp32 -> bf16 conversion for all six tensors (one dispatch).
// ---------------------------------------------------------------------------
__global__ void cvt_all_k(
    const float* __restrict__ x,  const float* __restrict__ qw,
    const float* __restrict__ kw, const float* __restrict__ vw,
    const float* __restrict__ fw, const float* __restrict__ ew,
    u16* __restrict__ xh,  u16* __restrict__ qwh, u16* __restrict__ kwh,
    u16* __restrict__ vwh, u16* __restrict__ fwh, u16* __restrict__ ewh)
{
    const int blk = blockIdx.x;
    const float* s; u16* d; int off;
    if (blk < 4096)      { s = x;  d = xh;  off = blk; }
    else if (blk < 5120) { s = qw; d = qwh; off = blk - 4096; }
    else if (blk < 6144) { s = kw; d = kwh; off = blk - 5120; }
    else if (blk < 7168) { s = vw; d = vwh; off = blk - 6144; }
    else if (blk < 8192) { s = fw; d = fwh; off = blk - 7168; }
    else                 { s = ew; d = ewh; off = blk - 8192; }
    const size_t i = (size_t)off * 256 + threadIdx.x;
    const float4 v = *(const float4*)(s + i * 4);
    ushort4 H = {f2bf(v.x), f2bf(v.y), f2bf(v.z), f2bf(v.w)};
    *(ushort4*)(d + i * 4) = H;
}

// ---------------------------------------------------------------------------
// RoPE cos/sin table: tab[s*32 + d1] = {cos, sin}(s * 10000^(-d1/32))
// ---------------------------------------------------------------------------
__global__ void rope_tab_kernel(float2* __restrict__ tab)
{
    const int idx = blockIdx.x * 256 + threadIdx.x;   // < 65536
    const int s = idx >> 5, d1 = idx & 31;
    const float inv = exp2f(-(float)d1 * 0.41524101186091903f); // log2(1e4)/32
    float sn, cs;
    sincosf((float)s * inv, &sn, &cs);
    tab[idx] = make_float2(cs, sn);
}

// ---------------------------------------------------------------------------
// Fused Q/K/V projection GEMM (z selects weight). 128x128 tile, BK=32.
// z<2: RoPE (table) epilogue, head-major [b][h][s][d] bf16.
//      z==0 (Q) additionally scaled by QSCALE (folds softmax 1/8 and log2e).
// z=2: transposed store Vt[b][h][d][s].
// ---------------------------------------------------------------------------
__global__ __launch_bounds__(256,2) void gemm_qkv(
    const u16* __restrict__ Ah,
    const u16* __restrict__ qwh, const u16* __restrict__ kwh,
    const u16* __restrict__ vwh,
    const float* __restrict__ q_b, const float* __restrict__ k_b,
    const float* __restrict__ v_b,
    const float2* __restrict__ tab,
    u16* __restrict__ Qhb, u16* __restrict__ Khb, u16* __restrict__ Vtb)
{
    __shared__ __align__(16) u16 sA[128*32], sB[128*32];
    const int z = blockIdx.z;
    const u16* Bh = (z == 0) ? qwh : (z == 1) ? kwh : vwh;
    const float* bias = (z == 0) ? q_b : (z == 1) ? k_b : v_b;
    const int t = threadIdx.x;
    const int m0 = blockIdx.y * 128, n0 = blockIdx.x * 128;
    const int lane = t & 63, w = t >> 6;
    const int wm = w >> 1, wn = w & 1;
    const int lr = lane & 15, qd = lane >> 4;
    f32x4 acc[4][4] = {};
    const size_t gA = (size_t)(m0 + (t >> 2)) * E_ + (t & 3) * 8;
    const size_t gB = (size_t)(n0 + (t >> 2)) * E_ + (t & 3) * 8;
    for (int k0 = 0; k0 < E_; k0 += 32) {
        #pragma unroll
        for (int is = 0; is < 2; is++) {
            const int ldo = (is * 256 + (t & 192)) * 16;
            const size_t ro = (size_t)is * 64 * E_;
            gl2lds16(Ah + gA + ro + k0, (char*)sA + ldo);
            gl2lds16(Bh + gB + ro + k0, (char*)sB + ldo);
        }
        __syncthreads();
        bf16x8 af[4], bfr[4];
        #pragma unroll
        for (int i = 0; i < 4; i++) {
            af[i]  = *(const bf16x8*)&sA[(wm*64 + i*16 + lr)*32 + qd*8];
            bfr[i] = *(const bf16x8*)&sB[(wn*64 + i*16 + lr)*32 + qd*8];
        }
        #pragma unroll
        for (int i = 0; i < 4; i++)
            #pragma unroll
            for (int j = 0; j < 4; j++)
                acc[i][j] = MFMA16(af[i], bfr[j], acc[i][j]);
        __syncthreads();
    }
    const int head = (n0 + wn * 64) >> 6;
    if (z < 2) {
        u16* Oh = (z == 0) ? Qhb : Khb;
        const float osc = (z == 0) ? QSCALE : 1.0f;
        #pragma unroll
        for (int j = 0; j < 2; j++) {
            const int d1 = j * 16 + lr;
            const float b1 = bias[head * 64 + d1];
            const float b2 = bias[head * 64 + d1 + 32];
            #pragma unroll
            for (int i = 0; i < 4; i++) {
                #pragma unroll
                for (int r = 0; r < 4; r++) {
                    const int tok = m0 + wm*64 + i*16 + qd*4 + r;
                    const int bb = tok >> 11, ss = tok & (S_ - 1);
                    const float2 t2 = tab[ss * 32 + d1];
                    const float q1 = acc[i][j][r]   + b1;
                    const float q2 = acc[i][j+2][r] + b2;
                    const size_t o = (((size_t)bb * H_ + head) * S_ + ss) * 64 + d1;
                    Oh[o]    = f2bf((q1 * t2.x - q2 * t2.y) * osc);
                    Oh[o+32] = f2bf((q2 * t2.x + q1 * t2.y) * osc);
                }
            }
        }
    } else {
        #pragma unroll
        for (int j = 0; j < 4; j++) {
            const int d = j * 16 + lr;
            const float bv = bias[head * 64 + d];
            #pragma unroll
            for (int i = 0; i < 4; i++)
                #pragma unroll
                for (int r = 0; r < 4; r++) {
                    const int tok = m0 + wm*64 + i*16 + qd*4 + r;
                    const int bb = tok >> 11, ss = tok & (S_ - 1);
                    Vtb[(((size_t)bb * H_ + head) * 64 + d) * S_ + ss] = f2bf(acc[i][j][r] + bv);
                }
        }
    }
}

// ---------------------------------------------------------------------------
// Flash attention, split-S partials. Block = (128 q, h, b, s-chunk of 1024).
// QK^T with SWAPPED operands (A=K, B=Q): lane regs hold 4 consecutive keys
// of one q-row -> P packs to one ds_write_b64 per subtile. p = exp2(S)
// (scale folded into Q). No-max softmax -> partial O (f32) + partial lsum.
// ---------------------------------------------------------------------------
__global__ __launch_bounds__(256,4) void attn_kernel(
    const u16* __restrict__ Q, const u16* __restrict__ K,
    const u16* __restrict__ Vt,
    float* __restrict__ Opart, float* __restrict__ lpart)
{
    __shared__ __align__(16) u16 sK[64*64];        // frag-major
    __shared__ __align__(16) u16 sV[64*64];        // frag-major
    __shared__ __align__(16) u16 sP[4][2][16*40];  // per-wave, per-strip
    const int t = threadIdx.x, lane = t & 63, w = t >> 6;
    const int lr = lane & 15, qd = lane >> 4;
    const int q0 = blockIdx.x * 128;
    const int h = blockIdx.y;
    const int b = blockIdx.z & 1, sc = blockIdx.z >> 1;
    const size_t bhS = ((size_t)b * H_ + h) * S_;
    const size_t bhD = ((size_t)b * H_ + h) * 64;
    bf16x8 qf[2][2];
    #pragma unroll
    for (int p = 0; p < 2; p++) {
        const size_t qa = (bhS + q0 + p*64 + w*16 + lr) * 64 + qd * 8;
        qf[p][0] = *(const bf16x8*)&Q[qa];
        qf[p][1] = *(const bf16x8*)&Q[qa + 32];
    }
    f32x4 O[2][4] = {};
    float lsum[2] = {};
    const int jbeg = sc * 1024, jend = jbeg + 1024;
    for (int j0 = jbeg; j0 < jend; j0 += 64) {
        #pragma unroll
        for (int it = 0; it < 2; it++) {
            const int CH = (it*4 + w)*4 + qd;
            const int sbs = CH >> 3;
            const int doff = ((CH >> 2) & 1)*32 + (CH & 3)*8;
            gl2lds16(&K [(bhS + j0 + sbs*16 + lr)*64 + doff],
                     (char*)sK + (it*4 + w)*1024);
            gl2lds16(&Vt[(bhD + sbs*16 + lr)*S_ + j0 + doff],
                     (char*)sV + (it*4 + w)*1024);
        }
        __syncthreads();
        // S^T = K Q^T for both strips (K frags shared): D[key][q]
        f32x4 Sv[2][4];
        #pragma unroll
        for (int sb = 0; sb < 4; sb++) {
            bf16x8 k0 = *(const bf16x8*)&sK[(sb*8 + qd)*128 + lr*8];
            bf16x8 k1 = *(const bf16x8*)&sK[(sb*8 + 4 + qd)*128 + lr*8];
            f32x4 a0 = {}, a1 = {};
            a0 = MFMA16(k0, qf[0][0], a0);
            a0 = MFMA16(k1, qf[0][1], a0);
            a1 = MFMA16(k0, qf[1][0], a1);
            a1 = MFMA16(k1, qf[1][1], a1);
            Sv[0][sb] = a0;
            Sv[1][sb] = a1;
        }
        // p = exp2(S); regs r = 4 consecutive keys (qd*4+r) of q-row lr.
        // Pack pairs (trunc bf16) -> one b64 LDS write per subtile.
        #pragma unroll
        for (int p = 0; p < 2; p++) {
            float ps = 0.f;
            #pragma unroll
            for (int sb = 0; sb < 4; sb++) {
                const float pv0 = exp2f(Sv[p][sb][0]);
                const float pv1 = exp2f(Sv[p][sb][1]);
                const float pv2 = exp2f(Sv[p][sb][2]);
                const float pv3 = exp2f(Sv[p][sb][3]);
                ps += (pv0 + pv1) + (pv2 + pv3);
                const u32 w0 = (__float_as_uint(pv0) >> 16) |
                               (__float_as_uint(pv1) & 0xffff0000u);
                const u32 w1 = (__float_as_uint(pv2) >> 16) |
                               (__float_as_uint(pv3) & 0xffff0000u);
                uint2 pk; pk.x = w0; pk.y = w1;
                *(uint2*)&sP[w][p][lr*40 + sb*16 + qd*4] = pk;
            }
            lsum[p] += ps;
        }
        // PV: V frags read ONCE, used by both strips
        {
            bf16x8 vv[8];
            #pragma unroll
            for (int ds = 0; ds < 4; ds++) {
                vv[2*ds]   = *(const bf16x8*)&sV[(ds*8 + qd)*128 + lr*8];
                vv[2*ds+1] = *(const bf16x8*)&sV[(ds*8 + 4 + qd)*128 + lr*8];
            }
            #pragma unroll
            for (int p = 0; p < 2; p++) {
                bf16x8 p0 = *(const bf16x8*)&sP[w][p][lr*40 + qd*8];
                bf16x8 p1 = *(const bf16x8*)&sP[w][p][lr*40 + 32 + qd*8];
                #pragma unroll
                for (int ds = 0; ds < 4; ds++) {
                    O[p][ds] = MFMA16(p0, vv[2*ds],   O[p][ds]);
                    O[p][ds] = MFMA16(p1, vv[2*ds+1], O[p][ds]);
                }
            }
        }
        __syncthreads();
    }
    float* Op = Opart + (size_t)sc * TOKENS * E_;
    float* lp = lpart + (size_t)sc * TOKENS * H_;
    // lsum is per q-row lr, partial over qd groups -> reduce lanes lr+16*qd
    #pragma unroll
    for (int p = 0; p < 2; p++) {
        float s2 = lsum[p];
        s2 += __shfl_xor(s2, 16, 64);
        s2 += __shfl_xor(s2, 32, 64);
        lsum[p] = s2;
    }
    if (lane < 16) {
        #pragma unroll
        for (int p = 0; p < 2; p++)
            lp[(size_t)(b*S_ + q0 + p*64 + w*16 + lane) * H_ + h] = lsum[p];
    }
    #pragma unroll
    for (int p = 0; p < 2; p++) {
        const int qb = q0 + p*64 + w*16 + qd*4;
        #pragma unroll
        for (int ds = 0; ds < 4; ds++)
            #pragma unroll
            for (int r = 0; r < 4; r++)
                Op[(size_t)(b*S_ + qb + r) * E_ + h*64 + ds*16 + lr] = O[p][ds][r];
    }
}

// ---------------------------------------------------------------------------
// Combine split-S partials + gate + top2, one block per token.
// O = (O1+O2)/(l1+l2) -> attn_bf (bf16); gate logits in-register (fp32).
// ---------------------------------------------------------------------------
__global__ __launch_bounds__(256) void combine_gate(
    const float* __restrict__ Opart, const float* __restrict__ lpart,
    const float* __restrict__ gate_w, const float* __restrict__ gate_b,
    u16* __restrict__ attn_bf, float* __restrict__ gval, int* __restrict__ eidx)
{
    __shared__ float red[4][NE_];
    __shared__ float lg8[NE_];
    const int tok = blockIdx.x;
    const int t = threadIdx.x;
    const int d4 = t * 4;
    const int h = d4 >> 6;
    const float l = lpart[(size_t)tok*H_ + h] + lpart[(size_t)(TOKENS + tok)*H_ + h];
    const float inv = 1.f / l;
    const float4 o1 = *(const float4*)&Opart[(size_t)tok*E_ + d4];
    const float4 o2 = *(const float4*)&Opart[(size_t)(TOKENS + tok)*E_ + d4];
    float v[4] = {(o1.x+o2.x)*inv, (o1.y+o2.y)*inv, (o1.z+o2.z)*inv, (o1.w+o2.w)*inv};
    ushort4 H4 = {f2bf(v[0]), f2bf(v[1]), f2bf(v[2]), f2bf(v[3])};
    *(ushort4*)&attn_bf[(size_t)tok*E_ + d4] = H4;
    float pe[NE_];
    #pragma unroll
    for (int e = 0; e < NE_; e++) {
        const float4 g = *(const float4*)&gate_w[e*E_ + d4];
        pe[e] = v[0]*g.x + v[1]*g.y + v[2]*g.z + v[3]*g.w;
    }
    #pragma unroll
    for (int e = 0; e < NE_; e++) {
        #pragma unroll
        for (int off = 32; off >= 1; off >>= 1)
            pe[e] += __shfl_xor(pe[e], off, 64);
    }
    const int w = t >> 6;
    if ((t & 63) == 0) {
        #pragma unroll
        for (int e = 0; e < NE_; e++) red[w][e] = pe[e];
    }
    __syncthreads();
    if (t < NE_)
        lg8[t] = red[0][t] + red[1][t] + red[2][t] + red[3][t] + gate_b[t];
    __syncthreads();
    if (t == 0) {
        float lg[NE_];
        #pragma unroll
        for (int e = 0; e < NE_; e++) lg[e] = lg8[e];
        float m = lg[0];
        #pragma unroll
        for (int e = 1; e < NE_; e++) m = fmaxf(m, lg[e]);
        float ex[NE_], ssum = 0.f;
        #pragma unroll
        for (int e = 0; e < NE_; e++) { ex[e] = __expf(lg[e]-m); ssum += ex[e]; }
        const float invs = 1.f / ssum;
        int i0 = 0;
        #pragma unroll
        for (int e = 1; e < NE_; e++) if (lg[e] > lg[i0]) i0 = e;
        int i1 = (i0 == 0) ? 1 : 0;
        #pragma unroll
        for (int e = 0; e < NE_; e++) if (e != i0 && lg[e] > lg[i1]) i1 = e;
        eidx[tok*2]     = i0;
        gval[tok*2]     = ex[i0]*invs;
        eidx[tok*2 + 1] = i1;
        gval[tok*2 + 1] = ex[i1]*invs;
    }
}

// ---------------------------------------------------------------------------
// Build per-expert token lists: LDS histogram per block (512 entries),
// then 8 global atomics per block to reserve ranges, then scatter.
// ---------------------------------------------------------------------------
__global__ __launch_bounds__(256) void build_lists_kernel(
    const int* __restrict__ eidx, int* __restrict__ list, int* __restrict__ counts)
{
    __shared__ int lcnt[NE_], lbase[NE_];
    const int t = threadIdx.x;
    if (t < NE_) lcnt[t] = 0;
    __syncthreads();
    const int ent = blockIdx.x * 512 + t * 2;
    const int e0 = eidx[ent], e1 = eidx[ent + 1];
    const int p0 = atomicAdd(&lcnt[e0], 1);
    const int p1 = atomicAdd(&lcnt[e1], 1);
    __syncthreads();
    if (t < NE_) lbase[t] = atomicAdd(&counts[t], lcnt[t]);
    __syncthreads();
    list[e0 * TOKENS + lbase[e0] + p0] = ent;
    list[e1 * TOKENS + lbase[e1] + p1] = ent + 1;
}

// ---------------------------------------------------------------------------
// Gathered expert GEMM (bf16): sel[ent] = g * (attn[tok] @ ew[e]^T + eb[e])
// ---------------------------------------------------------------------------
__global__ __launch_bounds__(256,2) void gemm_expert(
    const u16* __restrict__ Abf, const u16* __restrict__ ewh,
    const float* __restrict__ eb, const int* __restrict__ list,
    const int* __restrict__ counts, const float* __restrict__ gval,
    u16* __restrict__ sel)
{
    const int e = blockIdx.z;
    const int cnt = counts[e];
    const int m0 = blockIdx.y * 128;
    if (m0 >= cnt) return;
    __shared__ __align__(16) u16 sA[128*32], sB[128*32];
    __shared__ int sEnt[128];
    const int t = threadIdx.x;
    if (t < 128) sEnt[t] = (m0 + t < cnt) ? list[e * TOKENS + m0 + t] : -1;
    __syncthreads();
    const int n0 = blockIdx.x * 128;
    const int lane = t & 63, w = t >> 6;
    const int wm = w >> 1, wn = w & 1;
    const int lr = lane & 15, qd = lane >> 4;
    const int e0 = sEnt[t >> 2], e1 = sEnt[64 + (t >> 2)];
    const u16* ga0 = Abf + (size_t)(e0 < 0 ? 0 : (e0 >> 1)) * E_ + (t & 3) * 8;
    const u16* ga1 = Abf + (size_t)(e1 < 0 ? 0 : (e1 >> 1)) * E_ + (t & 3) * 8;
    const u16* gb0 = ewh + (size_t)e * E_ * E_ + (size_t)(n0 + (t >> 2)) * E_ + (t & 3) * 8;
    const u16* gb1 = gb0 + 64 * E_;
    f32x4 acc[4][4] = {};
    for (int k0 = 0; k0 < E_; k0 += 32) {
        {
            const int l0 = (t & 192) * 16;
            const int l1 = (256 + (t & 192)) * 16;
            gl2lds16(ga0 + k0, (char*)sA + l0);
            gl2lds16(ga1 + k0, (char*)sA + l1);
            gl2lds16(gb0 + k0, (char*)sB + l0);
            gl2lds16(gb1 + k0, (char*)sB + l1);
        }
        __syncthreads();
        bf16x8 af[4], bfr[4];
        #pragma unroll
        for (int i = 0; i < 4; i++) {
            af[i]  = *(const bf16x8*)&sA[(wm*64 + i*16 + lr)*32 + qd*8];
            bfr[i] = *(const bf16x8*)&sB[(wn*64 + i*16 + lr)*32 + qd*8];
        }
        #pragma unroll
        for (int i = 0; i < 4; i++)
            #pragma unroll
            for (int j = 0; j < 4; j++)
                acc[i][j] = MFMA16(af[i], bfr[j], acc[i][j]);
        __syncthreads();
    }
    #pragma unroll
    for (int i = 0; i < 4; i++)
        #pragma unroll
        for (int r = 0; r < 4; r++) {
            const int local = wm*64 + i*16 + qd*4 + r;
            const int ent = sEnt[local];
            if (ent < 0) continue;
            const float g = gval[ent];
            #pragma unroll
            for (int j = 0; j < 4; j++) {
                const int col = n0 + wn*64 + j*16 + lr;
                sel[(size_t)ent * E_ + col] = f2bf((acc[i][j][r] + eb[e * E_ + col]) * g);
            }
        }
}

// ---------------------------------------------------------------------------
// moe[tok] = sel[tok*2] + sel[tok*2+1]  (bf16 in/out)
// ---------------------------------------------------------------------------
__global__ void combine_kernel(const u16* __restrict__ sel, u16* __restrict__ moe)
{
    const int g = blockIdx.x * 256 + threadIdx.x;
    const int tok = g >> 8;
    const int c = (g & 255) * 4;
    const u16* a = sel + (size_t)tok * 2048 + c;
    float o[4];
    #pragma unroll
    for (int j = 0; j < 4; j++) o[j] = bf2f(a[j]) + bf2f(a[1024 + j]);
    ushort4 R = {f2bf(o[0]), f2bf(o[1]), f2bf(o[2]), f2bf(o[3])};
    *(ushort4*)(moe + (size_t)tok * E_ + c) = R;
}

// ---------------------------------------------------------------------------
// FFN GEMM (bf16) + bias + fp32 residual -> fp32 out
// ---------------------------------------------------------------------------
__global__ __launch_bounds__(256,2) void gemm_ffn(
    const u16* __restrict__ Ah, const u16* __restrict__ Bh,
    const float* __restrict__ bias, const float* __restrict__ res,
    float* __restrict__ C)
{
    __shared__ __align__(16) u16 sA[128*32], sB[128*32];
    const int t = threadIdx.x;
    const int m0 = blockIdx.y * 128, n0 = blockIdx.x * 128;
    const int lane = t & 63, w = t >> 6;
    const int wm = w >> 1, wn = w & 1;
    const int lr = lane & 15, qd = lane >> 4;
    f32x4 acc[4][4] = {};
    const size_t gA = (size_t)(m0 + (t >> 2)) * E_ + (t & 3) * 8;
    const size_t gB = (size_t)(n0 + (t >> 2)) * E_ + (t & 3) * 8;
    for (int k0 = 0; k0 < E_; k0 += 32) {
        #pragma unroll
        for (int is = 0; is < 2; is++) {
            const int ldo = (is * 256 + (t & 192)) * 16;
            const size_t ro = (size_t)is * 64 * E_;
            gl2lds16(Ah + gA + ro + k0, (char*)sA + ldo);
            gl2lds16(Bh + gB + ro + k0, (char*)sB + ldo);
        }
        __syncthreads();
        bf16x8 af[4], bfr[4];
        #pragma unroll
        for (int i = 0; i < 4; i++) {
            af[i]  = *(const bf16x8*)&sA[(wm*64 + i*16 + lr)*32 + qd*8];
            bfr[i] = *(const bf16x8*)&sB[(wn*64 + i*16 + lr)*32 + qd*8];
        }
        #pragma unroll
        for (int i = 0; i < 4; i++)
            #pragma unroll
            for (int j = 0; j < 4; j++)
                acc[i][j] = MFMA16(af[i], bfr[j], acc[i][j]);
        __syncthreads();
    }
    #pragma unroll
    for (int i = 0; i < 4; i++)
        #pragma unroll
        for (int r = 0; r < 4; r++) {
            const int tok = m0 + wm*64 + i*16 + qd*4 + r;
            #pragma unroll
            for (int j = 0; j < 4; j++) {
                const int col = n0 + wn*64 + j*16 + lr;
                C[(size_t)tok * E_ + col] = acc[i][j][r] + bias[col] + res[(size_t)tok * E_ + col];
            }
        }
}

// ---------------------------------------------------------------------------
extern "C" void kernel_launch(void* const* d_in, const int* in_sizes, int n_in,
                              void* d_out, int out_size, void* d_ws, size_t ws_size,
                              hipStream_t stream) {
    const float* x      = (const float*)d_in[0];
    const float* q_w    = (const float*)d_in[1];
    const float* q_b    = (const float*)d_in[2];
    const float* k_w    = (const float*)d_in[3];
    const float* k_b    = (const float*)d_in[4];
    const float* v_w    = (const float*)d_in[5];
    const float* v_b    = (const float*)d_in[6];
    const float* gate_w = (const float*)d_in[7];
    const float* gate_b = (const float*)d_in[8];
    const float* ew     = (const float*)d_in[9];
    const float* eb     = (const float*)d_in[10];
    const float* ffn_w  = (const float*)d_in[11];
    const float* ffn_b  = (const float*)d_in[12];
    float* out = (float*)d_out;

    char* p = (char*)d_ws;
    auto alloc = [&](size_t bytes) { char* r = p; p += (bytes + 255) & ~(size_t)255; return r; };
    u16* xh   = (u16*)alloc((size_t)TOKENS*E_*2);
    u16* qwh  = (u16*)alloc((size_t)E_*E_*2);
    u16* kwh  = (u16*)alloc((size_t)E_*E_*2);
    u16* vwh  = (u16*)alloc((size_t)E_*E_*2);
    u16* fwh  = (u16*)alloc((size_t)E_*E_*2);
    u16* ewh  = (u16*)alloc((size_t)NE_*E_*E_*2);
    u16* Qhb  = (u16*)alloc((size_t)TOKENS*E_*2);
    u16* Khb  = (u16*)alloc((size_t)TOKENS*E_*2);
    u16* Vtb  = (u16*)alloc((size_t)TOKENS*E_*2);
    u16* abf  = (u16*)alloc((size_t)TOKENS*E_*2);
    float* Opart = (float*)alloc((size_t)2*TOKENS*E_*4);
    float* lpart = (float*)alloc((size_t)2*TOKENS*H_*4);
    u16* selb = (u16*)alloc((size_t)2*TOKENS*E_*2);
    u16* moeb = (u16*)alloc((size_t)TOKENS*E_*2);
    float2* rtab = (float2*)alloc((size_t)S_*32*8);
    float* gvl = (float*)alloc((size_t)2*TOKENS*4);
    int*   eix = (int*)alloc((size_t)2*TOKENS*4);
    int*   lst = (int*)alloc((size_t)NE_*TOKENS*4);
    int*   cnt = (int*)alloc(256);

    hipMemsetAsync(cnt, 0, 256, stream);

    rope_tab_kernel<<<S_*32/256, 256, 0, stream>>>(rtab);
    cvt_all_k<<<16384, 256, 0, stream>>>(x, q_w, k_w, v_w, ffn_w, ew,
                                         xh, qwh, kwh, vwh, fwh, ewh);

    gemm_qkv<<<dim3(8,32,3), 256, 0, stream>>>(xh, qwh, kwh, vwh,
                                               q_b, k_b, v_b, rtab,
                                               Qhb, Khb, Vtb);

    attn_kernel<<<dim3(16,16,4), 256, 0, stream>>>(Qhb, Khb, Vtb, Opart, lpart);

    combine_gate<<<TOKENS, 256, 0, stream>>>(Opart, lpart, gate_w, gate_b,
                                             abf, gvl, eix);
    build_lists_kernel<<<TOKENS/256, 256, 0, stream>>>(eix, lst, cnt);
    gemm_expert<<<dim3(8,32,8), 256, 0, stream>>>(abf, ewh, eb, lst, cnt, gvl, selb);
    combine_kernel<<<4096, 256, 0, stream>>>(selb, moeb);
    gemm_ffn<<<dim3(8,32), 256, 0, stream>>>(moeb, fwh, ffn_b, x, out);
}

// Round 8
// 294.572 us; speedup vs baseline: 1.0427x; 1.0427x over previous
//
#include <hip/hip_runtime.h>
#include <hip/hip_bf16.h>

#define B_ 2
#define S_ 2048
#define E_ 1024
#define H_ 16
#define D_ 64
#define NE_ 8
#define TOKENS (B_*S_)   // 4096
#define QSCALE 0.18033688011112043f   // log2(e)/8, folded into Q

typedef __attribute__((ext_vector_type(8))) short bf16x8;
typedef __attribute__((ext_vector_type(4))) float f32x4;
typedef unsigned short u16;
typedef unsigned int u32;

#if __has_builtin(__builtin_amdgcn_exp2f)
#define EXP2(x) __builtin_amdgcn_exp2f(x)
#else
#define EXP2(x) exp2f(x)
#endif

__device__ __forceinline__ u16 f2bf(float f) {
    u32 u = __float_as_uint(f);
    u32 r = u + 0x7fffu + ((u >> 16) & 1u);
    return (u16)(r >> 16);
}
__device__ __forceinline__ float bf2f(u16 h) {
    return __uint_as_float(((u32)h) << 16);
}
__device__ __forceinline__ void gl2lds16(const void* g, void* l) {
    __builtin_amdgcn_global_load_lds(
        (__attribute__((address_space(1))) void*)(g),
        (__attribute__((address_space(3))) void*)(l), 16, 0, 0);
}
#define MFMA16(a,b,c) __builtin_amdgcn_mfma_f32_16x16x32_bf16(a,b,c,0,0,0)

// ---------------------------------------------------------------------------
// Fused fp32 -> bf16 conversion for all six tensors + RoPE table (one dispatch).
// Blocks 0..16383: conversions. Blocks 16384..16639: cos/sin table.
// ---------------------------------------------------------------------------
__global__ void cvt_all_k(
    const float* __restrict__ x,  const float* __restrict__ qw,
    const float* __restrict__ kw, const float* __restrict__ vw,
    const float* __restrict__ fw, const float* __restrict__ ew,
    u16* __restrict__ xh,  u16* __restrict__ qwh, u16* __restrict__ kwh,
    u16* __restrict__ vwh, u16* __restrict__ fwh, u16* __restrict__ ewh,
    float2* __restrict__ tab)
{
    const int blk = blockIdx.x;
    if (blk >= 16384) {
        const int idx = (blk - 16384) * 256 + threadIdx.x;   // < 65536
        const int s = idx >> 5, d1 = idx & 31;
        const float inv = exp2f(-(float)d1 * 0.41524101186091903f);
        float sn, cs;
        sincosf((float)s * inv, &sn, &cs);
        tab[idx] = make_float2(cs, sn);
        return;
    }
    const float* s; u16* d; int off;
    if (blk < 4096)      { s = x;  d = xh;  off = blk; }
    else if (blk < 5120) { s = qw; d = qwh; off = blk - 4096; }
    else if (blk < 6144) { s = kw; d = kwh; off = blk - 5120; }
    else if (blk < 7168) { s = vw; d = vwh; off = blk - 6144; }
    else if (blk < 8192) { s = fw; d = fwh; off = blk - 7168; }
    else                 { s = ew; d = ewh; off = blk - 8192; }
    const size_t i = (size_t)off * 256 + threadIdx.x;
    const float4 v = *(const float4*)(s + i * 4);
    ushort4 H = {f2bf(v.x), f2bf(v.y), f2bf(v.z), f2bf(v.w)};
    *(ushort4*)(d + i * 4) = H;
}

// ---------------------------------------------------------------------------
// Fused Q/K/V projection GEMM (z selects weight). 128x128 tile, BK=32.
// z<2: RoPE (table) epilogue, head-major [b][h][s][d] bf16.
//      z==0 (Q) additionally scaled by QSCALE (folds softmax 1/8 and log2e).
// z=2: transposed store Vt[b][h][d][s].
// ---------------------------------------------------------------------------
__global__ __launch_bounds__(256,2) void gemm_qkv(
    const u16* __restrict__ Ah,
    const u16* __restrict__ qwh, const u16* __restrict__ kwh,
    const u16* __restrict__ vwh,
    const float* __restrict__ q_b, const float* __restrict__ k_b,
    const float* __restrict__ v_b,
    const float2* __restrict__ tab,
    u16* __restrict__ Qhb, u16* __restrict__ Khb, u16* __restrict__ Vtb)
{
    __shared__ __align__(16) u16 sA[128*32], sB[128*32];
    const int z = blockIdx.z;
    const u16* Bh = (z == 0) ? qwh : (z == 1) ? kwh : vwh;
    const float* bias = (z == 0) ? q_b : (z == 1) ? k_b : v_b;
    const int t = threadIdx.x;
    const int m0 = blockIdx.y * 128, n0 = blockIdx.x * 128;
    const int lane = t & 63, w = t >> 6;
    const int wm = w >> 1, wn = w & 1;
    const int lr = lane & 15, qd = lane >> 4;
    f32x4 acc[4][4] = {};
    const size_t gA = (size_t)(m0 + (t >> 2)) * E_ + (t & 3) * 8;
    const size_t gB = (size_t)(n0 + (t >> 2)) * E_ + (t & 3) * 8;
    for (int k0 = 0; k0 < E_; k0 += 32) {
        #pragma unroll
        for (int is = 0; is < 2; is++) {
            const int ldo = (is * 256 + (t & 192)) * 16;
            const size_t ro = (size_t)is * 64 * E_;
            gl2lds16(Ah + gA + ro + k0, (char*)sA + ldo);
            gl2lds16(Bh + gB + ro + k0, (char*)sB + ldo);
        }
        __syncthreads();
        bf16x8 af[4], bfr[4];
        #pragma unroll
        for (int i = 0; i < 4; i++) {
            af[i]  = *(const bf16x8*)&sA[(wm*64 + i*16 + lr)*32 + qd*8];
            bfr[i] = *(const bf16x8*)&sB[(wn*64 + i*16 + lr)*32 + qd*8];
        }
        #pragma unroll
        for (int i = 0; i < 4; i++)
            #pragma unroll
            for (int j = 0; j < 4; j++)
                acc[i][j] = MFMA16(af[i], bfr[j], acc[i][j]);
        __syncthreads();
    }
    const int head = (n0 + wn * 64) >> 6;
    if (z < 2) {
        u16* Oh = (z == 0) ? Qhb : Khb;
        const float osc = (z == 0) ? QSCALE : 1.0f;
        #pragma unroll
        for (int j = 0; j < 2; j++) {
            const int d1 = j * 16 + lr;
            const float b1 = bias[head * 64 + d1];
            const float b2 = bias[head * 64 + d1 + 32];
            #pragma unroll
            for (int i = 0; i < 4; i++) {
                #pragma unroll
                for (int r = 0; r < 4; r++) {
                    const int tok = m0 + wm*64 + i*16 + qd*4 + r;
                    const int bb = tok >> 11, ss = tok & (S_ - 1);
                    const float2 t2 = tab[ss * 32 + d1];
                    const float q1 = acc[i][j][r]   + b1;
                    const float q2 = acc[i][j+2][r] + b2;
                    const size_t o = (((size_t)bb * H_ + head) * S_ + ss) * 64 + d1;
                    Oh[o]    = f2bf((q1 * t2.x - q2 * t2.y) * osc);
                    Oh[o+32] = f2bf((q2 * t2.x + q1 * t2.y) * osc);
                }
            }
        }
    } else {
        #pragma unroll
        for (int j = 0; j < 4; j++) {
            const int d = j * 16 + lr;
            const float bv = bias[head * 64 + d];
            #pragma unroll
            for (int i = 0; i < 4; i++)
                #pragma unroll
                for (int r = 0; r < 4; r++) {
                    const int tok = m0 + wm*64 + i*16 + qd*4 + r;
                    const int bb = tok >> 11, ss = tok & (S_ - 1);
                    Vtb[(((size_t)bb * H_ + head) * 64 + d) * S_ + ss] = f2bf(acc[i][j][r] + bv);
                }
        }
    }
}

// ---------------------------------------------------------------------------
// Flash attention, split-S partials. Block = (128 q, h, b, s-chunk of 1024).
// Swapped-operand QK^T (regs = 4 consecutive keys); p = exp2(S) single v_exp;
// pack via v_perm (1 op/pair); lsum via ones-MFMA (row-sums in matrix pipe).
// ---------------------------------------------------------------------------
__global__ __launch_bounds__(256,4) void attn_kernel(
    const u16* __restrict__ Q, const u16* __restrict__ K,
    const u16* __restrict__ Vt,
    float* __restrict__ Opart, float* __restrict__ lpart)
{
    __shared__ __align__(16) u16 sK[64*64];        // frag-major
    __shared__ __align__(16) u16 sV[64*64];        // frag-major
    __shared__ __align__(16) u16 sP[4][2][16*40];  // per-wave, per-strip
    const int t = threadIdx.x, lane = t & 63, w = t >> 6;
    const int lr = lane & 15, qd = lane >> 4;
    const int q0 = blockIdx.x * 128;
    const int h = blockIdx.y;
    const int b = blockIdx.z & 1, sc = blockIdx.z >> 1;
    const size_t bhS = ((size_t)b * H_ + h) * S_;
    const size_t bhD = ((size_t)b * H_ + h) * 64;
    bf16x8 qf[2][2];
    #pragma unroll
    for (int p = 0; p < 2; p++) {
        const size_t qa = (bhS + q0 + p*64 + w*16 + lr) * 64 + qd * 8;
        qf[p][0] = *(const bf16x8*)&Q[qa];
        qf[p][1] = *(const bf16x8*)&Q[qa + 32];
    }
    bf16x8 vOnes;
    #pragma unroll
    for (int i = 0; i < 8; i++) vOnes[i] = (short)0x3F80;
    f32x4 O[2][4] = {};
    f32x4 Ol[2] = {};
    const int jbeg = sc * 1024, jend = jbeg + 1024;
    for (int j0 = jbeg; j0 < jend; j0 += 64) {
        #pragma unroll
        for (int it = 0; it < 2; it++) {
            const int CH = (it*4 + w)*4 + qd;
            const int sbs = CH >> 3;
            const int doff = ((CH >> 2) & 1)*32 + (CH & 3)*8;
            gl2lds16(&K [(bhS + j0 + sbs*16 + lr)*64 + doff],
                     (char*)sK + (it*4 + w)*1024);
            gl2lds16(&Vt[(bhD + sbs*16 + lr)*S_ + j0 + doff],
                     (char*)sV + (it*4 + w)*1024);
        }
        __syncthreads();
        // S^T = K Q^T for both strips (K frags shared): D[key][q]
        f32x4 Sv[2][4];
        #pragma unroll
        for (int sb = 0; sb < 4; sb++) {
            bf16x8 k0 = *(const bf16x8*)&sK[(sb*8 + qd)*128 + lr*8];
            bf16x8 k1 = *(const bf16x8*)&sK[(sb*8 + 4 + qd)*128 + lr*8];
            f32x4 a0 = {}, a1 = {};
            a0 = MFMA16(k0, qf[0][0], a0);
            a0 = MFMA16(k1, qf[0][1], a0);
            a1 = MFMA16(k0, qf[1][0], a1);
            a1 = MFMA16(k1, qf[1][1], a1);
            Sv[0][sb] = a0;
            Sv[1][sb] = a1;
        }
        // p = exp2(S) (one v_exp each); pack pairs via v_perm -> b64 write
        #pragma unroll
        for (int p = 0; p < 2; p++) {
            #pragma unroll
            for (int sb = 0; sb < 4; sb++) {
                const float pv0 = EXP2(Sv[p][sb][0]);
                const float pv1 = EXP2(Sv[p][sb][1]);
                const float pv2 = EXP2(Sv[p][sb][2]);
                const float pv3 = EXP2(Sv[p][sb][3]);
                uint2 pk;
                pk.x = __builtin_amdgcn_perm(__float_as_uint(pv1),
                                             __float_as_uint(pv0), 0x07060302u);
                pk.y = __builtin_amdgcn_perm(__float_as_uint(pv3),
                                             __float_as_uint(pv2), 0x07060302u);
                *(uint2*)&sP[w][p][lr*40 + sb*16 + qd*4] = pk;
            }
        }
        // PV: V frags read ONCE, used by both strips; lsum via ones-MFMA
        {
            bf16x8 vv[8];
            #pragma unroll
            for (int ds = 0; ds < 4; ds++) {
                vv[2*ds]   = *(const bf16x8*)&sV[(ds*8 + qd)*128 + lr*8];
                vv[2*ds+1] = *(const bf16x8*)&sV[(ds*8 + 4 + qd)*128 + lr*8];
            }
            #pragma unroll
            for (int p = 0; p < 2; p++) {
                bf16x8 p0 = *(const bf16x8*)&sP[w][p][lr*40 + qd*8];
                bf16x8 p1 = *(const bf16x8*)&sP[w][p][lr*40 + 32 + qd*8];
                #pragma unroll
                for (int ds = 0; ds < 4; ds++) {
                    O[p][ds] = MFMA16(p0, vv[2*ds],   O[p][ds]);
                    O[p][ds] = MFMA16(p1, vv[2*ds+1], O[p][ds]);
                }
                Ol[p] = MFMA16(p0, vOnes, Ol[p]);
                Ol[p] = MFMA16(p1, vOnes, Ol[p]);
            }
        }
        __syncthreads();
    }
    float* Op = Opart + (size_t)sc * TOKENS * E_;
    float* lp = lpart + (size_t)sc * TOKENS * H_;
    // Ol rows (qd*4+r) hold lsum replicated across cols; lane lr==0 writes.
    if (lr == 0) {
        #pragma unroll
        for (int p = 0; p < 2; p++)
            #pragma unroll
            for (int r = 0; r < 4; r++)
                lp[(size_t)(b*S_ + q0 + p*64 + w*16 + qd*4 + r) * H_ + h] = Ol[p][r];
    }
    #pragma unroll
    for (int p = 0; p < 2; p++) {
        const int qb = q0 + p*64 + w*16 + qd*4;
        #pragma unroll
        for (int ds = 0; ds < 4; ds++)
            #pragma unroll
            for (int r = 0; r < 4; r++)
                Op[(size_t)(b*S_ + qb + r) * E_ + h*64 + ds*16 + lr] = O[p][ds][r];
    }
}

// ---------------------------------------------------------------------------
// Combine split-S partials + gate + top2, one block per token.
// ---------------------------------------------------------------------------
__global__ __launch_bounds__(256) void combine_gate(
    const float* __restrict__ Opart, const float* __restrict__ lpart,
    const float* __restrict__ gate_w, const float* __restrict__ gate_b,
    u16* __restrict__ attn_bf, float* __restrict__ gval, int* __restrict__ eidx)
{
    __shared__ float red[4][NE_];
    __shared__ float lg8[NE_];
    const int tok = blockIdx.x;
    const int t = threadIdx.x;
    const int d4 = t * 4;
    const int h = d4 >> 6;
    const float l = lpart[(size_t)tok*H_ + h] + lpart[(size_t)(TOKENS + tok)*H_ + h];
    const float inv = 1.f / l;
    const float4 o1 = *(const float4*)&Opart[(size_t)tok*E_ + d4];
    const float4 o2 = *(const float4*)&Opart[(size_t)(TOKENS + tok)*E_ + d4];
    float v[4] = {(o1.x+o2.x)*inv, (o1.y+o2.y)*inv, (o1.z+o2.z)*inv, (o1.w+o2.w)*inv};
    ushort4 H4 = {f2bf(v[0]), f2bf(v[1]), f2bf(v[2]), f2bf(v[3])};
    *(ushort4*)&attn_bf[(size_t)tok*E_ + d4] = H4;
    float pe[NE_];
    #pragma unroll
    for (int e = 0; e < NE_; e++) {
        const float4 g = *(const float4*)&gate_w[e*E_ + d4];
        pe[e] = v[0]*g.x + v[1]*g.y + v[2]*g.z + v[3]*g.w;
    }
    #pragma unroll
    for (int e = 0; e < NE_; e++) {
        #pragma unroll
        for (int off = 32; off >= 1; off >>= 1)
            pe[e] += __shfl_xor(pe[e], off, 64);
    }
    const int w = t >> 6;
    if ((t & 63) == 0) {
        #pragma unroll
        for (int e = 0; e < NE_; e++) red[w][e] = pe[e];
    }
    __syncthreads();
    if (t < NE_)
        lg8[t] = red[0][t] + red[1][t] + red[2][t] + red[3][t] + gate_b[t];
    __syncthreads();
    if (t == 0) {
        float lg[NE_];
        #pragma unroll
        for (int e = 0; e < NE_; e++) lg[e] = lg8[e];
        float m = lg[0];
        #pragma unroll
        for (int e = 1; e < NE_; e++) m = fmaxf(m, lg[e]);
        float ex[NE_], ssum = 0.f;
        #pragma unroll
        for (int e = 0; e < NE_; e++) { ex[e] = __expf(lg[e]-m); ssum += ex[e]; }
        const float invs = 1.f / ssum;
        int i0 = 0;
        #pragma unroll
        for (int e = 1; e < NE_; e++) if (lg[e] > lg[i0]) i0 = e;
        int i1 = (i0 == 0) ? 1 : 0;
        #pragma unroll
        for (int e = 0; e < NE_; e++) if (e != i0 && lg[e] > lg[i1]) i1 = e;
        eidx[tok*2]     = i0;
        gval[tok*2]     = ex[i0]*invs;
        eidx[tok*2 + 1] = i1;
        gval[tok*2 + 1] = ex[i1]*invs;
    }
}

// ---------------------------------------------------------------------------
// Build per-expert token lists: LDS histogram per block (512 entries),
// then 8 global atomics per block to reserve ranges, then scatter.
// ---------------------------------------------------------------------------
__global__ __launch_bounds__(256) void build_lists_kernel(
    const int* __restrict__ eidx, int* __restrict__ list, int* __restrict__ counts)
{
    __shared__ int lcnt[NE_], lbase[NE_];
    const int t = threadIdx.x;
    if (t < NE_) lcnt[t] = 0;
    __syncthreads();
    const int ent = blockIdx.x * 512 + t * 2;
    const int e0 = eidx[ent], e1 = eidx[ent + 1];
    const int p0 = atomicAdd(&lcnt[e0], 1);
    const int p1 = atomicAdd(&lcnt[e1], 1);
    __syncthreads();
    if (t < NE_) lbase[t] = atomicAdd(&counts[t], lcnt[t]);
    __syncthreads();
    list[e0 * TOKENS + lbase[e0] + p0] = ent;
    list[e1 * TOKENS + lbase[e1] + p1] = ent + 1;
}

// ---------------------------------------------------------------------------
// Gathered expert GEMM (bf16): sel[ent] = g * (attn[tok] @ ew[e]^T + eb[e])
// ---------------------------------------------------------------------------
__global__ __launch_bounds__(256,2) void gemm_expert(
    const u16* __restrict__ Abf, const u16* __restrict__ ewh,
    const float* __restrict__ eb, const int* __restrict__ list,
    const int* __restrict__ counts, const float* __restrict__ gval,
    u16* __restrict__ sel)
{
    const int e = blockIdx.z;
    const int cnt = counts[e];
    const int m0 = blockIdx.y * 128;
    if (m0 >= cnt) return;
    __shared__ __align__(16) u16 sA[128*32], sB[128*32];
    __shared__ int sEnt[128];
    const int t = threadIdx.x;
    if (t < 128) sEnt[t] = (m0 + t < cnt) ? list[e * TOKENS + m0 + t] : -1;
    __syncthreads();
    const int n0 = blockIdx.x * 128;
    const int lane = t & 63, w = t >> 6;
    const int wm = w >> 1, wn = w & 1;
    const int lr = lane & 15, qd = lane >> 4;
    const int e0 = sEnt[t >> 2], e1 = sEnt[64 + (t >> 2)];
    const u16* ga0 = Abf + (size_t)(e0 < 0 ? 0 : (e0 >> 1)) * E_ + (t & 3) * 8;
    const u16* ga1 = Abf + (size_t)(e1 < 0 ? 0 : (e1 >> 1)) * E_ + (t & 3) * 8;
    const u16* gb0 = ewh + (size_t)e * E_ * E_ + (size_t)(n0 + (t >> 2)) * E_ + (t & 3) * 8;
    const u16* gb1 = gb0 + 64 * E_;
    f32x4 acc[4][4] = {};
    for (int k0 = 0; k0 < E_; k0 += 32) {
        {
            const int l0 = (t & 192) * 16;
            const int l1 = (256 + (t & 192)) * 16;
            gl2lds16(ga0 + k0, (char*)sA + l0);
            gl2lds16(ga1 + k0, (char*)sA + l1);
            gl2lds16(gb0 + k0, (char*)sB + l0);
            gl2lds16(gb1 + k0, (char*)sB + l1);
        }
        __syncthreads();
        bf16x8 af[4], bfr[4];
        #pragma unroll
        for (int i = 0; i < 4; i++) {
            af[i]  = *(const bf16x8*)&sA[(wm*64 + i*16 + lr)*32 + qd*8];
            bfr[i] = *(const bf16x8*)&sB[(wn*64 + i*16 + lr)*32 + qd*8];
        }
        #pragma unroll
        for (int i = 0; i < 4; i++)
            #pragma unroll
            for (int j = 0; j < 4; j++)
                acc[i][j] = MFMA16(af[i], bfr[j], acc[i][j]);
        __syncthreads();
    }
    #pragma unroll
    for (int i = 0; i < 4; i++)
        #pragma unroll
        for (int r = 0; r < 4; r++) {
            const int local = wm*64 + i*16 + qd*4 + r;
            const int ent = sEnt[local];
            if (ent < 0) continue;
            const float g = gval[ent];
            #pragma unroll
            for (int j = 0; j < 4; j++) {
                const int col = n0 + wn*64 + j*16 + lr;
                sel[(size_t)ent * E_ + col] = f2bf((acc[i][j][r] + eb[e * E_ + col]) * g);
            }
        }
}

// ---------------------------------------------------------------------------
// moe[tok] = sel[tok*2] + sel[tok*2+1]  (bf16 in/out)
// ---------------------------------------------------------------------------
__global__ void combine_kernel(const u16* __restrict__ sel, u16* __restrict__ moe)
{
    const int g = blockIdx.x * 256 + threadIdx.x;
    const int tok = g >> 8;
    const int c = (g & 255) * 4;
    const u16* a = sel + (size_t)tok * 2048 + c;
    float o[4];
    #pragma unroll
    for (int j = 0; j < 4; j++) o[j] = bf2f(a[j]) + bf2f(a[1024 + j]);
    ushort4 R = {f2bf(o[0]), f2bf(o[1]), f2bf(o[2]), f2bf(o[3])};
    *(ushort4*)(moe + (size_t)tok * E_ + c) = R;
}

// ---------------------------------------------------------------------------
// FFN GEMM (bf16) + bias + fp32 residual -> fp32 out
// ---------------------------------------------------------------------------
__global__ __launch_bounds__(256,2) void gemm_ffn(
    const u16* __restrict__ Ah, const u16* __restrict__ Bh,
    const float* __restrict__ bias, const float* __restrict__ res,
    float* __restrict__ C)
{
    __shared__ __align__(16) u16 sA[128*32], sB[128*32];
    const int t = threadIdx.x;
    const int m0 = blockIdx.y * 128, n0 = blockIdx.x * 128;
    const int lane = t & 63, w = t >> 6;
    const int wm = w >> 1, wn = w & 1;
    const int lr = lane & 15, qd = lane >> 4;
    f32x4 acc[4][4] = {};
    const size_t gA = (size_t)(m0 + (t >> 2)) * E_ + (t & 3) * 8;
    const size_t gB = (size_t)(n0 + (t >> 2)) * E_ + (t & 3) * 8;
    for (int k0 = 0; k0 < E_; k0 += 32) {
        #pragma unroll
        for (int is = 0; is < 2; is++) {
            const int ldo = (is * 256 + (t & 192)) * 16;
            const size_t ro = (size_t)is * 64 * E_;
            gl2lds16(Ah + gA + ro + k0, (char*)sA + ldo);
            gl2lds16(Bh + gB + ro + k0, (char*)sB + ldo);
        }
        __syncthreads();
        bf16x8 af[4], bfr[4];
        #pragma unroll
        for (int i = 0; i < 4; i++) {
            af[i]  = *(const bf16x8*)&sA[(wm*64 + i*16 + lr)*32 + qd*8];
            bfr[i] = *(const bf16x8*)&sB[(wn*64 + i*16 + lr)*32 + qd*8];
        }
        #pragma unroll
        for (int i = 0; i < 4; i++)
            #pragma unroll
            for (int j = 0; j < 4; j++)
                acc[i][j] = MFMA16(af[i], bfr[j], acc[i][j]);
        __syncthreads();
    }
    #pragma unroll
    for (int i = 0; i < 4; i++)
        #pragma unroll
        for (int r = 0; r < 4; r++) {
            const int tok = m0 + wm*64 + i*16 + qd*4 + r;
            #pragma unroll
            for (int j = 0; j < 4; j++) {
                const int col = n0 + wn*64 + j*16 + lr;
                C[(size_t)tok * E_ + col] = acc[i][j][r] + bias[col] + res[(size_t)tok * E_ + col];
            }
        }
}

// ---------------------------------------------------------------------------
extern "C" void kernel_launch(void* const* d_in, const int* in_sizes, int n_in,
                              void* d_out, int out_size, void* d_ws, size_t ws_size,
                              hipStream_t stream) {
    const float* x      = (const float*)d_in[0];
    const float* q_w    = (const float*)d_in[1];
    const float* q_b    = (const float*)d_in[2];
    const float* k_w    = (const float*)d_in[3];
    const float* k_b    = (const float*)d_in[4];
    const float* v_w    = (const float*)d_in[5];
    const float* v_b    = (const float*)d_in[6];
    const float* gate_w = (const float*)d_in[7];
    const float* gate_b = (const float*)d_in[8];
    const float* ew     = (const float*)d_in[9];
    const float* eb     = (const float*)d_in[10];
    const float* ffn_w  = (const float*)d_in[11];
    const float* ffn_b  = (const float*)d_in[12];
    float* out = (float*)d_out;

    char* p = (char*)d_ws;
    auto alloc = [&](size_t bytes) { char* r = p; p += (bytes + 255) & ~(size_t)255; return r; };
    u16* xh   = (u16*)alloc((size_t)TOKENS*E_*2);
    u16* qwh  = (u16*)alloc((size_t)E_*E_*2);
    u16* kwh  = (u16*)alloc((size_t)E_*E_*2);
    u16* vwh  = (u16*)alloc((size_t)E_*E_*2);
    u16* fwh  = (u16*)alloc((size_t)E_*E_*2);
    u16* ewh  = (u16*)alloc((size_t)NE_*E_*E_*2);
    u16* Qhb  = (u16*)alloc((size_t)TOKENS*E_*2);
    u16* Khb  = (u16*)alloc((size_t)TOKENS*E_*2);
    u16* Vtb  = (u16*)alloc((size_t)TOKENS*E_*2);
    u16* abf  = (u16*)alloc((size_t)TOKENS*E_*2);
    float* Opart = (float*)alloc((size_t)2*TOKENS*E_*4);
    float* lpart = (float*)alloc((size_t)2*TOKENS*H_*4);
    u16* selb = (u16*)alloc((size_t)2*TOKENS*E_*2);
    u16* moeb = (u16*)alloc((size_t)TOKENS*E_*2);
    float2* rtab = (float2*)alloc((size_t)S_*32*8);
    float* gvl = (float*)alloc((size_t)2*TOKENS*4);
    int*   eix = (int*)alloc((size_t)2*TOKENS*4);
    int*   lst = (int*)alloc((size_t)NE_*TOKENS*4);
    int*   cnt = (int*)alloc(256);

    hipMemsetAsync(cnt, 0, 256, stream);

    cvt_all_k<<<16640, 256, 0, stream>>>(x, q_w, k_w, v_w, ffn_w, ew,
                                         xh, qwh, kwh, vwh, fwh, ewh, rtab);

    gemm_qkv<<<dim3(8,32,3), 256, 0, stream>>>(xh, qwh, kwh, vwh,
                                               q_b, k_b, v_b, rtab,
                                               Qhb, Khb, Vtb);

    attn_kernel<<<dim3(16,16,4), 256, 0, stream>>>(Qhb, Khb, Vtb, Opart, lpart);

    combine_gate<<<TOKENS, 256, 0, stream>>>(Opart, lpart, gate_w, gate_b,
                                             abf, gvl, eix);
    build_lists_kernel<<<TOKENS/256, 256, 0, stream>>>(eix, lst, cnt);
    gemm_expert<<<dim3(8,32,8), 256, 0, stream>>>(abf, ewh, eb, lst, cnt, gvl, selb);
    combine_kernel<<<4096, 256, 0, stream>>>(selb, moeb);
    gemm_ffn<<<dim3(8,32), 256, 0, stream>>>(moeb, fwh, ffn_b, x, out);
}